// Round 20
// baseline (274.210 us; speedup 1.0000x reference)
//
#include <hip/hip_runtime.h>
#include <cstddef>

#define T_LEN 1000
#define B_SZ 64
#define C_IN_ 12
#define D_MODEL_ 128
#define D_INNER_ 256
#define D_STATE_ 16
#define DT_RANK_ 8
#define N_CLS 5
#define NCH 10      // scan time-chunks (100 steps each)
#define CIT 25      // float4 iters per chunk

typedef __attribute__((ext_vector_type(8))) short bf16x8;
typedef __attribute__((ext_vector_type(8))) unsigned short u16x8;
typedef __attribute__((ext_vector_type(4))) float f32x4;

__device__ __forceinline__ float fast_exp2(float x) {
#if __has_builtin(__builtin_amdgcn_exp2f)
  return __builtin_amdgcn_exp2f(x);
#else
  float r; asm volatile("v_exp_f32 %0, %1" : "=v"(r) : "v"(x)); return r;
#endif
}
__device__ __forceinline__ float fast_log2(float x) {
#if __has_builtin(__builtin_amdgcn_logf)
  return __builtin_amdgcn_logf(x);
#else
  float r; asm volatile("v_log_f32 %0, %1" : "=v"(r) : "v"(x)); return r;
#endif
}
__device__ __forceinline__ float fast_rcp(float x) {
#if __has_builtin(__builtin_amdgcn_rcpf)
  return __builtin_amdgcn_rcpf(x);
#else
  float r; asm volatile("v_rcp_f32 %0, %1" : "=v"(r) : "v"(x)); return r;
#endif
}
__device__ __forceinline__ float silu_f(float x) {
  float den = 1.f + fast_exp2(-x * 1.4426950408889634f);
  return x * fast_rcp(den);
}
__device__ __forceinline__ float softplus_f(float x) {
  const float L = 1.4426950408889634f, iL = 0.6931471805599453f;
  float e = fast_exp2(-fabsf(x) * L);
  float l = fast_log2(1.f + e) * iL;
  return fmaxf(x, 0.f) + l;
}
__device__ __forceinline__ unsigned short f2bf(float f) {
  unsigned u = __builtin_bit_cast(unsigned, f);
  u = u + 0x7FFFu + ((u >> 16) & 1u);   // RNE
  return (unsigned short)(u >> 16);
}
__device__ __forceinline__ float bf2f(unsigned short h) {
  unsigned u = ((unsigned)h) << 16;
  return __builtin_bit_cast(float, u);
}

// K0: h = x@ip_w.T + ip_b (bf16, MFMA-frag-packed, zero-filled t>=1000) + W pack.
__global__ __launch_bounds__(256) void k0_prep(
    const float* __restrict__ x, const float* __restrict__ ip_w,
    const float* __restrict__ ip_b, const float* __restrict__ in_proj_w,
    char* __restrict__ h_pk, char* __restrict__ w_pk)
{
  __shared__ unsigned short pk_s[8192];
  __shared__ unsigned short pkw_s[32768];
  const int tid = threadIdx.x;

  if (blockIdx.x == 16) {                    // W-pack block
    if (blockIdx.y != 0) return;
    const int n = tid;
    for (int k = 0; k < D_MODEL_; ++k) {
      unsigned short v = f2bf(in_proj_w[(size_t)n * D_MODEL_ + k]);
      int off = ((n >> 4) * 4 + (k >> 5)) * 512 + ((k & 31) >> 3) * 128
              + (n & 15) * 8 + (k & 7);
      pkw_s[off] = v;
    }
    __syncthreads();
    const float4* s4 = (const float4*)pkw_s;
    float4* dst = (float4*)w_pk;
#pragma unroll
    for (int q = 0; q < 16; ++q) dst[tid * 16 + q] = s4[tid * 16 + q];
    return;
  }

  const int tile4 = blockIdx.x;
  const int b = blockIdx.y;
  const int rl = tid & 63;
  const int kc = (tid >> 6) * 32;
  const int t = tile4 * 64 + rl;

  float xr[C_IN_] = {0.f, 0.f, 0.f, 0.f, 0.f, 0.f, 0.f, 0.f, 0.f, 0.f, 0.f, 0.f};
  const bool valid = (t < T_LEN);
  if (valid) {
    const float4* xp = (const float4*)(x + ((size_t)b * T_LEN + t) * C_IN_);
    float4 v0 = xp[0], v1 = xp[1], v2 = xp[2];
    xr[0] = v0.x; xr[1] = v0.y; xr[2] = v0.z;  xr[3] = v0.w;
    xr[4] = v1.x; xr[5] = v1.y; xr[6] = v1.z;  xr[7] = v1.w;
    xr[8] = v2.x; xr[9] = v2.y; xr[10] = v2.z; xr[11] = v2.w;
  }
  for (int kk = 0; kk < 32; ++kk) {
    const int k = kc + kk;
    unsigned short v = 0;
    if (valid) {
      float acc = ip_b[k];
      const float* wr = ip_w + k * C_IN_;
#pragma unroll
      for (int c = 0; c < C_IN_; ++c) acc += xr[c] * wr[c];
      v = f2bf(acc);
    }
    int off = (rl >> 4) * 2048 + (k >> 5) * 512 + ((k & 31) >> 3) * 128
            + (rl & 15) * 8 + (k & 7);
    pk_s[off] = v;
  }
  __syncthreads();
  const float4* s4 = (const float4*)pk_s;
  float4* dst = (float4*)(h_pk + (size_t)(b * 64 + tile4 * 4) * 4096);
#pragma unroll
  for (int q = 0; q < 4; ++q) dst[tid * 4 + q] = s4[tid * 4 + q];
}

// K1 v10 (R16-proven): MFMA bf16 GEMM; halo rows also via MFMA.
__global__ __launch_bounds__(256) void k1_u(
    const char* __restrict__ h_pk, const char* __restrict__ w_pk,
    const float* __restrict__ conv_w, const float* __restrict__ conv_b,
    float* __restrict__ u_out)
{
  __shared__ float xm[67][260];

  const int tile = blockIdx.x;
  const int b    = blockIdx.y;
  const int t0   = tile * 64;
  const int tid  = threadIdx.x;
  const int w    = tid >> 6;
  const int l    = tid & 63;

  {
    const char* achunk = h_pk + (size_t)(b * 64 + tile * 4 + w) * 4096;
    bf16x8 a0 = *(const bf16x8*)(achunk + 0 * 1024 + l * 16);
    bf16x8 a1 = *(const bf16x8*)(achunk + 1 * 1024 + l * 16);
    bf16x8 a2 = *(const bf16x8*)(achunk + 2 * 1024 + l * 16);
    bf16x8 a3 = *(const bf16x8*)(achunk + 3 * 1024 + l * 16);

    const int row_l = w * 16 + (l >> 4) * 4;
#pragma unroll
    for (int nt = 0; nt < 16; ++nt) {
      const char* wb = w_pk + (size_t)nt * 4096 + l * 16;
      bf16x8 b0 = *(const bf16x8*)(wb + 0 * 1024);
      bf16x8 b1 = *(const bf16x8*)(wb + 1 * 1024);
      bf16x8 b2 = *(const bf16x8*)(wb + 2 * 1024);
      bf16x8 b3 = *(const bf16x8*)(wb + 3 * 1024);
      f32x4 acc = {0.f, 0.f, 0.f, 0.f};
      acc = __builtin_amdgcn_mfma_f32_16x16x32_bf16(a0, b0, acc, 0, 0, 0);
      acc = __builtin_amdgcn_mfma_f32_16x16x32_bf16(a1, b1, acc, 0, 0, 0);
      acc = __builtin_amdgcn_mfma_f32_16x16x32_bf16(a2, b2, acc, 0, 0, 0);
      acc = __builtin_amdgcn_mfma_f32_16x16x32_bf16(a3, b3, acc, 0, 0, 0);
      const int col = nt * 16 + (l & 15);
#pragma unroll
      for (int r = 0; r < 4; ++r)
        xm[3 + row_l + r][col] = acc[r];
    }
  }

  if (tile > 0) {
    const char* hchunk = h_pk + (size_t)(b * 64 + tile * 4 - 1) * 4096;
    bf16x8 ha0 = *(const bf16x8*)(hchunk + 0 * 1024 + l * 16);
    bf16x8 ha1 = *(const bf16x8*)(hchunk + 1 * 1024 + l * 16);
    bf16x8 ha2 = *(const bf16x8*)(hchunk + 2 * 1024 + l * 16);
    bf16x8 ha3 = *(const bf16x8*)(hchunk + 3 * 1024 + l * 16);
#pragma unroll
    for (int q = 0; q < 4; ++q) {
      const int nt = w * 4 + q;
      const char* wb = w_pk + (size_t)nt * 4096 + l * 16;
      bf16x8 b0 = *(const bf16x8*)(wb + 0 * 1024);
      bf16x8 b1 = *(const bf16x8*)(wb + 1 * 1024);
      bf16x8 b2 = *(const bf16x8*)(wb + 2 * 1024);
      bf16x8 b3 = *(const bf16x8*)(wb + 3 * 1024);
      f32x4 acc = {0.f, 0.f, 0.f, 0.f};
      acc = __builtin_amdgcn_mfma_f32_16x16x32_bf16(ha0, b0, acc, 0, 0, 0);
      acc = __builtin_amdgcn_mfma_f32_16x16x32_bf16(ha1, b1, acc, 0, 0, 0);
      acc = __builtin_amdgcn_mfma_f32_16x16x32_bf16(ha2, b2, acc, 0, 0, 0);
      acc = __builtin_amdgcn_mfma_f32_16x16x32_bf16(ha3, b3, acc, 0, 0, 0);
      if (l >= 48) {
        const int col = nt * 16 + (l & 15);
        xm[0][col] = acc[1];
        xm[1][col] = acc[2];
        xm[2][col] = acc[3];
      }
    }
  } else {
#pragma unroll
    for (int r = 0; r < 3; ++r) xm[r][tid] = 0.f;
  }
  __syncthreads();

  {
    const int n = tid;
    const float4 cw = *(const float4*)&conv_w[n * 4];
    const float  cb = conv_b[n];
    float x0 = xm[0][n], x1 = xm[1][n], x2 = xm[2][n];
    for (int i = 0; i < 64; ++i) {
      const int t = t0 + i;
      float x3 = xm[3 + i][n];
      if (t < T_LEN) {
        float s = cb + x0 * cw.x + x1 * cw.y + x2 * cw.z + x3 * cw.w;
        u_out[(((size_t)b * T_LEN + t) << 8) + n] = silu_f(s);
      }
      x0 = x1; x1 = x2; x2 = x3;
    }
  }
}

// K3 v13: phase1 dbc GEMM; phase2 LDS-transpose-bounced full-line stores of
// delta_T/du_T [b][d][1000]; bm now TRANSPOSED bm_T[b][n][1000] (k4 reads it
// as per-thread-contiguous b128 rows, no LDS); u_last stashed.
__global__ __launch_bounds__(256) void k3_delta(
    const float* __restrict__ u, const float* __restrict__ x_proj_w,
    const float* __restrict__ dt_proj_w, const float* __restrict__ dt_proj_b,
    float* __restrict__ delta_T, float* __restrict__ du_T,
    float* __restrict__ bm_T, float* __restrict__ u_last)
{
  __shared__ __align__(16) float smem[24 * 65 * 4];
  float4 (*xp4)[65] = reinterpret_cast<float4(*)[65]>(smem);   // phase 1 view
  float* tx = smem;                                            // phase 2 view
  __shared__ float dt_s[64][9];
  __shared__ float bm_s[64][17];

  const int row0 = blockIdx.x * 64;
  const int tid = threadIdx.x;

  for (int f = tid; f < 24 * 64; f += 256) {
    int c = f >> 6, k4 = f & 63;
    xp4[c][k4] = *(const float4*)&x_proj_w[(size_t)c * 256 + k4 * 4];
  }
  const float4 w0 = *(const float4*)&dt_proj_w[(size_t)tid * 8];
  const float4 w1 = *(const float4*)&dt_proj_w[(size_t)tid * 8 + 4];
  const float bias = dt_proj_b[tid];
  __syncthreads();

  // phase 1
  {
    const int r2 = tid >> 3, cg = tid & 7;
    const int ra = 2 * r2;
    const float4* ua4 = (const float4*)(u + (size_t)(row0 + ra) * 256);
    const float4* ub4 = (const float4*)(u + (size_t)(row0 + ra + 1) * 256);
    float a0 = 0.f, a1 = 0.f, a2 = 0.f, b0 = 0.f, b1 = 0.f, b2 = 0.f;
    for (int k4 = 0; k4 < 64; ++k4) {
      float4 a = ua4[k4], bb = ub4[k4];
      float4 q0 = xp4[cg * 3 + 0][k4];
      float4 q1 = xp4[cg * 3 + 1][k4];
      float4 q2 = xp4[cg * 3 + 2][k4];
      a0 += a.x * q0.x + a.y * q0.y + a.z * q0.z + a.w * q0.w;
      a1 += a.x * q1.x + a.y * q1.y + a.z * q1.z + a.w * q1.w;
      a2 += a.x * q2.x + a.y * q2.y + a.z * q2.z + a.w * q2.w;
      b0 += bb.x * q0.x + bb.y * q0.y + bb.z * q0.z + bb.w * q0.w;
      b1 += bb.x * q1.x + bb.y * q1.y + bb.z * q1.z + bb.w * q1.w;
      b2 += bb.x * q2.x + bb.y * q2.y + bb.z * q2.z + bb.w * q2.w;
    }
    float va[2][3] = {{a0, a1, a2}, {b0, b1, b2}};
#pragma unroll
    for (int rr = 0; rr < 2; ++rr)
#pragma unroll
      for (int c = 0; c < 3; ++c) {
        int col = cg * 3 + c;
        int row = ra + rr;
        if (col < 8) dt_s[row][col] = va[rr][c];
        else bm_s[row][col - 8] = va[rr][c];
      }
  }
  __syncthreads();   // phase-1 xp4 reads done; tx may overwrite

  // phase 2: 4 chunks of 16 t; LDS transpose -> full-line coalesced stores
  for (int c16 = 0; c16 < 4; ++c16) {
    float dd[16], uu[16];
#pragma unroll
    for (int j = 0; j < 16; ++j) {
      int r = c16 * 16 + j;
      float pre = bias
        + dt_s[r][0] * w0.x + dt_s[r][1] * w0.y + dt_s[r][2] * w0.z + dt_s[r][3] * w0.w
        + dt_s[r][4] * w1.x + dt_s[r][5] * w1.y + dt_s[r][6] * w1.z + dt_s[r][7] * w1.w;
      float dlt = softplus_f(pre);
      size_t o = (size_t)(row0 + r) * 256 + tid;
      float uv = u[o];
      dd[j] = dlt;
      uu[j] = dlt * uv;
      int rowg = row0 + r;
      if ((rowg - (rowg / 1000) * 1000) == 999)
        u_last[(rowg / 1000) * 256 + tid] = uv;
    }
#pragma unroll
    for (int j = 0; j < 16; ++j) tx[tid * 17 + j] = dd[j];
    __syncthreads();
#pragma unroll
    for (int q = 0; q < 4; ++q) {
      int d_ = (tid >> 2) + 64 * q;
      int t4 = (tid & 3) * 4;
      float4 v = make_float4(tx[d_ * 17 + t4], tx[d_ * 17 + t4 + 1],
                             tx[d_ * 17 + t4 + 2], tx[d_ * 17 + t4 + 3]);
      int rowg = row0 + c16 * 16 + t4;
      int bb = rowg / 1000;
      int t = rowg - bb * 1000;
      *(float4*)&delta_T[((size_t)(bb * 256 + d_)) * 1000 + t] = v;
    }
    __syncthreads();
#pragma unroll
    for (int j = 0; j < 16; ++j) tx[tid * 17 + j] = uu[j];
    __syncthreads();
#pragma unroll
    for (int q = 0; q < 4; ++q) {
      int d_ = (tid >> 2) + 64 * q;
      int t4 = (tid & 3) * 4;
      float4 v = make_float4(tx[d_ * 17 + t4], tx[d_ * 17 + t4 + 1],
                             tx[d_ * 17 + t4 + 2], tx[d_ * 17 + t4 + 3]);
      int rowg = row0 + c16 * 16 + t4;
      int bb = rowg / 1000;
      int t = rowg - bb * 1000;
      *(float4*)&du_T[((size_t)(bb * 256 + d_)) * 1000 + t] = v;
    }
    __syncthreads();
  }
  // bm_T[b][n][1000]: thread = (n, tq); quads never straddle b (1000%4==0)
  {
    const int n = tid >> 4;
    const int tq = tid & 15;
    float4 v = make_float4(bm_s[tq * 4 + 0][n], bm_s[tq * 4 + 1][n],
                           bm_s[tq * 4 + 2][n], bm_s[tq * 4 + 3][n]);
    int rowg = row0 + tq * 4;
    int bb = rowg / 1000;
    int t = rowg - bb * 1000;
    *(float4*)&bm_T[((size_t)(bb * 16 + n)) * 1000 + t] = v;
  }
}

// K4 v18: ZERO LDS. thread = (b, d, n, chunk); all three operands read as
// global b128 from per-thread-contiguous rows (broadcast-coalesced), 4-deep
// STATIC circular prefetch (fully unrolled -> i&3 compile-time, no rotation
// movs, 12 loads in flight/wave). Fixes R18's LDS-pipe bound (47 cyc/iter)
// and R15's register starvation (bufs force VGPR>=64).
__global__ __launch_bounds__(256) void k4_scan(
    const float* __restrict__ delta_T, const float* __restrict__ du_T,
    const float* __restrict__ bm_T, const float* __restrict__ A_log,
    float* __restrict__ Qb, float* __restrict__ Pb)
{
  const int d0 = blockIdx.x * 16;
  const int b  = blockIdx.y;
  const int c  = blockIdx.z;
  const int tid = threadIdx.x;
  const int dl = tid >> 4;
  const int n  = tid & 15;
  const int d  = d0 + dl;

  const float A2 = -expf(A_log[(size_t)d * 16 + n]) * 1.4426950408889634f;
  const float* dp = delta_T + ((size_t)(b * 256 + d)) * 1000 + c * 100;
  const float* xp = du_T    + ((size_t)(b * 256 + d)) * 1000 + c * 100;
  const float* bp = bm_T    + ((size_t)(b * 16 + n)) * 1000 + c * 100;

  float4 db[4], xb[4], bb[4];
#pragma unroll
  for (int j = 0; j < 4; ++j) {
    db[j] = *(const float4*)(dp + 4 * j);
    xb[j] = *(const float4*)(xp + 4 * j);
    bb[j] = *(const float4*)(bp + 4 * j);
  }
  float s = 0.f, sum = 0.f;
#pragma unroll
  for (int i = 0; i < CIT; ++i) {
    float4 dv = db[i & 3], xv = xb[i & 3], bv = bb[i & 3];
    if (i + 4 < CIT) {
      db[i & 3] = *(const float4*)(dp + 4 * (i + 4));
      xb[i & 3] = *(const float4*)(xp + 4 * (i + 4));
      bb[i & 3] = *(const float4*)(bp + 4 * (i + 4));
    }
    sum += (dv.x + dv.y) + (dv.z + dv.w);
    s = fast_exp2(dv.x * A2) * s + xv.x * bv.x;
    s = fast_exp2(dv.y * A2) * s + xv.y * bv.y;
    s = fast_exp2(dv.z * A2) * s + xv.z * bv.z;
    s = fast_exp2(dv.w * A2) * s + xv.w * bv.w;
  }

  const size_t o = (size_t)c * 262144 + (size_t)b * 4096 + (size_t)d0 * 16 + tid;
  Qb[o] = s;
  Pb[o] = fast_exp2(A2 * sum);
}

// K4b: fold the NCH affine transitions -> final state.
__global__ __launch_bounds__(256) void k4b_combine(
    const float* __restrict__ Qb, const float* __restrict__ Pb,
    float* __restrict__ state_out)
{
  const size_t g = (size_t)blockIdx.x * 256 + threadIdx.x;   // 1024 blocks
  float s = Qb[g];
#pragma unroll
  for (int c = 1; c < NCH; ++c)
    s = Qb[(size_t)c * 262144 + g] + Pb[(size_t)c * 262144 + g] * s;
  state_out[g] = s;
}

// K5: per-batch head.
__global__ __launch_bounds__(256) void k5_head(
    const float* __restrict__ x, const float* __restrict__ ip_w,
    const float* __restrict__ ip_b, const float* __restrict__ in_proj_w,
    const float* __restrict__ x_proj_w, const float* __restrict__ u_last,
    const float* __restrict__ state, const float* __restrict__ D_skip,
    const float* __restrict__ out_proj_w, const float* __restrict__ fc1_w,
    const float* __restrict__ fc1_b, const float* __restrict__ fc2_w,
    const float* __restrict__ fc2_b, float* __restrict__ out)
{
  const int b = blockIdx.x, tid = threadIdx.x;
  __shared__ float hl[128], ul[256], zs[256], cm[16], yv[256], ov[128], hid[64];
  if (tid < 128) {
    float acc = ip_b[tid];
    const float* xr = x + ((size_t)b * T_LEN + (T_LEN - 1)) * C_IN_;
#pragma unroll
    for (int c = 0; c < C_IN_; ++c) acc += xr[c] * ip_w[tid * C_IN_ + c];
    hl[tid] = acc;
  }
  ul[tid] = u_last[b * 256 + tid];
  __syncthreads();
  {
    float acc = 0.f;
    const float4* wv = (const float4*)(in_proj_w + (size_t)(256 + tid) * 128);
    const float4* h4 = (const float4*)hl;
    for (int k = 0; k < 32; ++k) {
      float4 a = wv[k], c = h4[k];
      acc += c.x * a.x + c.y * a.y + c.z * a.z + c.w * a.w;
    }
    zs[tid] = silu_f(acc);
  }
  if (tid < 16) {
    float acc = 0.f;
    const float4* wv = (const float4*)(x_proj_w + (size_t)(24 + tid) * 256);
    const float4* u4 = (const float4*)ul;
    for (int k = 0; k < 64; ++k) {
      float4 a = wv[k], c = u4[k];
      acc += c.x * a.x + c.y * a.y + c.z * a.z + c.w * a.w;
    }
    cm[tid] = acc;
  }
  __syncthreads();
  {
    const float* st = state + ((size_t)b * 256 + tid) * 16;
    float acc = 0.f;
#pragma unroll
    for (int n = 0; n < 16; ++n) acc += st[n] * cm[n];
    yv[tid] = (acc + ul[tid] * D_skip[tid]) * zs[tid];
  }
  __syncthreads();
  if (tid < 128) {
    float acc = 0.f;
    const float4* wv = (const float4*)(out_proj_w + (size_t)tid * 256);
    const float4* y4 = (const float4*)yv;
    for (int k = 0; k < 64; ++k) {
      float4 a = wv[k], c = y4[k];
      acc += c.x * a.x + c.y * a.y + c.z * a.z + c.w * a.w;
    }
    ov[tid] = acc;
  }
  __syncthreads();
  if (tid < 64) {
    float acc = fc1_b[tid];
    const float4* wv = (const float4*)(fc1_w + (size_t)tid * 128);
    const float4* o4 = (const float4*)ov;
    for (int k = 0; k < 32; ++k) {
      float4 a = wv[k], c = o4[k];
      acc += c.x * a.x + c.y * a.y + c.z * a.z + c.w * a.w;
    }
    hid[tid] = fmaxf(acc, 0.f);
  }
  __syncthreads();
  if (tid < N_CLS) {
    float acc = fc2_b[tid];
    const float* wv = fc2_w + (size_t)tid * 64;
    for (int k = 0; k < 64; ++k) acc += hid[k] * wv[k];
    out[b * N_CLS + tid] = acc;
  }
}

extern "C" void kernel_launch(void* const* d_in, const int* in_sizes, int n_in,
                              void* d_out, int out_size, void* d_ws, size_t ws_size,
                              hipStream_t stream) {
  (void)in_sizes; (void)n_in; (void)out_size; (void)ws_size;
  const float* x         = (const float*)d_in[0];
  const float* ip_w      = (const float*)d_in[1];
  const float* ip_b      = (const float*)d_in[2];
  const float* in_proj_w = (const float*)d_in[3];
  const float* conv_w    = (const float*)d_in[4];
  const float* conv_b    = (const float*)d_in[5];
  const float* x_proj_w  = (const float*)d_in[6];
  const float* dt_proj_w = (const float*)d_in[7];
  const float* dt_proj_b = (const float*)d_in[8];
  const float* A_log     = (const float*)d_in[9];
  const float* D_skip    = (const float*)d_in[10];
  const float* out_proj_w= (const float*)d_in[11];
  const float* fc1_w     = (const float*)d_in[12];
  const float* fc1_b     = (const float*)d_in[13];
  const float* fc2_w     = (const float*)d_in[14];
  const float* fc2_b     = (const float*)d_in[15];
  float* out = (float*)d_out;

  float* u       = (float*)d_ws;                 // 16,384,000 f32 (65.5 MB)
  float* delta_T = u + (size_t)16384000;         // 16,384,000 f32 [b][256][1000]
  float* du_T    = delta_T + (size_t)16384000;   // 16,384,000 f32 [b][256][1000]
  float* bm      = du_T + (size_t)16384000;      //  1,024,000 f32 [b][16][1000]
  float* state   = bm + (size_t)1024000;         //    262,144 f32
  float* u_last  = state + (size_t)262144;       //     16,384 f32 (201.8 MB, proven)
  // aliases into regions dead at their use time (proven pattern):
  char* h_pk = (char*)delta_T;                   // k0..k1 (delta_T written later by k3)
  char* w_pk = h_pk + (size_t)64 * 64 * 4096;
  float* Qb  = u;                                // k4..k4b (u dead after k3)
  float* Pb  = u + (size_t)4000000;              // 2.62M fl each

  k0_prep<<<dim3(17, 64), 256, 0, stream>>>(x, ip_w, ip_b, in_proj_w, h_pk, w_pk);
  k1_u<<<dim3(16, 64), 256, 0, stream>>>(h_pk, w_pk, conv_w, conv_b, u);
  k3_delta<<<1000, 256, 0, stream>>>(u, x_proj_w, dt_proj_w, dt_proj_b,
                                     delta_T, du_T, bm, u_last);
  k4_scan<<<dim3(16, 64, NCH), 256, 0, stream>>>(delta_T, du_T, bm, A_log, Qb, Pb);
  k4b_combine<<<1024, 256, 0, stream>>>(Qb, Pb, state);
  k5_head<<<64, 256, 0, stream>>>(x, ip_w, ip_b, in_proj_w, x_proj_w, u_last, state,
                                  D_skip, out_proj_w, fc1_w, fc1_b, fc2_w, fc2_b, out);
}

// Round 21
// 209.362 us; speedup vs baseline: 1.3097x; 1.3097x over previous
//
#include <hip/hip_runtime.h>
#include <cstddef>

#define T_LEN 1000
#define B_SZ 64
#define C_IN_ 12
#define D_MODEL_ 128
#define D_INNER_ 256
#define D_STATE_ 16
#define DT_RANK_ 8
#define N_CLS 5
#define NCH 5       // scan time-chunks (200 steps each; keeps bf16 rows 16B-aligned)

typedef __attribute__((ext_vector_type(8))) short bf16x8;
typedef __attribute__((ext_vector_type(8))) unsigned short u16x8;
typedef __attribute__((ext_vector_type(4))) unsigned short u16x4;
typedef __attribute__((ext_vector_type(4))) float f32x4;

__device__ __forceinline__ float fast_exp2(float x) {
#if __has_builtin(__builtin_amdgcn_exp2f)
  return __builtin_amdgcn_exp2f(x);
#else
  float r; asm volatile("v_exp_f32 %0, %1" : "=v"(r) : "v"(x)); return r;
#endif
}
__device__ __forceinline__ float fast_log2(float x) {
#if __has_builtin(__builtin_amdgcn_logf)
  return __builtin_amdgcn_logf(x);
#else
  float r; asm volatile("v_log_f32 %0, %1" : "=v"(r) : "v"(x)); return r;
#endif
}
__device__ __forceinline__ float fast_rcp(float x) {
#if __has_builtin(__builtin_amdgcn_rcpf)
  return __builtin_amdgcn_rcpf(x);
#else
  float r; asm volatile("v_rcp_f32 %0, %1" : "=v"(r) : "v"(x)); return r;
#endif
}
__device__ __forceinline__ float silu_f(float x) {
  float den = 1.f + fast_exp2(-x * 1.4426950408889634f);
  return x * fast_rcp(den);
}
__device__ __forceinline__ float softplus_f(float x) {
  const float L = 1.4426950408889634f, iL = 0.6931471805599453f;
  float e = fast_exp2(-fabsf(x) * L);
  float l = fast_log2(1.f + e) * iL;
  return fmaxf(x, 0.f) + l;
}
__device__ __forceinline__ unsigned short f2bf(float f) {
  unsigned u = __builtin_bit_cast(unsigned, f);
  u = u + 0x7FFFu + ((u >> 16) & 1u);   // RNE
  return (unsigned short)(u >> 16);
}
__device__ __forceinline__ float bf2f(unsigned short h) {
  unsigned u = ((unsigned)h) << 16;
  return __builtin_bit_cast(float, u);
}

// K0: h = x@ip_w.T + ip_b (bf16, MFMA-frag-packed, zero-filled t>=1000) + W pack.
__global__ __launch_bounds__(256) void k0_prep(
    const float* __restrict__ x, const float* __restrict__ ip_w,
    const float* __restrict__ ip_b, const float* __restrict__ in_proj_w,
    char* __restrict__ h_pk, char* __restrict__ w_pk)
{
  __shared__ unsigned short pk_s[8192];
  __shared__ unsigned short pkw_s[32768];
  const int tid = threadIdx.x;

  if (blockIdx.x == 16) {                    // W-pack block
    if (blockIdx.y != 0) return;
    const int n = tid;
    for (int k = 0; k < D_MODEL_; ++k) {
      unsigned short v = f2bf(in_proj_w[(size_t)n * D_MODEL_ + k]);
      int off = ((n >> 4) * 4 + (k >> 5)) * 512 + ((k & 31) >> 3) * 128
              + (n & 15) * 8 + (k & 7);
      pkw_s[off] = v;
    }
    __syncthreads();
    const float4* s4 = (const float4*)pkw_s;
    float4* dst = (float4*)w_pk;
#pragma unroll
    for (int q = 0; q < 16; ++q) dst[tid * 16 + q] = s4[tid * 16 + q];
    return;
  }

  const int tile4 = blockIdx.x;
  const int b = blockIdx.y;
  const int rl = tid & 63;
  const int kc = (tid >> 6) * 32;
  const int t = tile4 * 64 + rl;

  float xr[C_IN_] = {0.f, 0.f, 0.f, 0.f, 0.f, 0.f, 0.f, 0.f, 0.f, 0.f, 0.f, 0.f};
  const bool valid = (t < T_LEN);
  if (valid) {
    const float4* xp = (const float4*)(x + ((size_t)b * T_LEN + t) * C_IN_);
    float4 v0 = xp[0], v1 = xp[1], v2 = xp[2];
    xr[0] = v0.x; xr[1] = v0.y; xr[2] = v0.z;  xr[3] = v0.w;
    xr[4] = v1.x; xr[5] = v1.y; xr[6] = v1.z;  xr[7] = v1.w;
    xr[8] = v2.x; xr[9] = v2.y; xr[10] = v2.z; xr[11] = v2.w;
  }
  for (int kk = 0; kk < 32; ++kk) {
    const int k = kc + kk;
    unsigned short v = 0;
    if (valid) {
      float acc = ip_b[k];
      const float* wr = ip_w + k * C_IN_;
#pragma unroll
      for (int c = 0; c < C_IN_; ++c) acc += xr[c] * wr[c];
      v = f2bf(acc);
    }
    int off = (rl >> 4) * 2048 + (k >> 5) * 512 + ((k & 31) >> 3) * 128
            + (rl & 15) * 8 + (k & 7);
    pk_s[off] = v;
  }
  __syncthreads();
  const float4* s4 = (const float4*)pk_s;
  float4* dst = (float4*)(h_pk + (size_t)(b * 64 + tile4 * 4) * 4096);
#pragma unroll
  for (int q = 0; q < 4; ++q) dst[tid * 4 + q] = s4[tid * 4 + q];
}

// K1 v10 (R16-proven): MFMA bf16 GEMM; halo rows also via MFMA.
__global__ __launch_bounds__(256) void k1_u(
    const char* __restrict__ h_pk, const char* __restrict__ w_pk,
    const float* __restrict__ conv_w, const float* __restrict__ conv_b,
    float* __restrict__ u_out)
{
  __shared__ float xm[67][260];

  const int tile = blockIdx.x;
  const int b    = blockIdx.y;
  const int t0   = tile * 64;
  const int tid  = threadIdx.x;
  const int w    = tid >> 6;
  const int l    = tid & 63;

  {
    const char* achunk = h_pk + (size_t)(b * 64 + tile * 4 + w) * 4096;
    bf16x8 a0 = *(const bf16x8*)(achunk + 0 * 1024 + l * 16);
    bf16x8 a1 = *(const bf16x8*)(achunk + 1 * 1024 + l * 16);
    bf16x8 a2 = *(const bf16x8*)(achunk + 2 * 1024 + l * 16);
    bf16x8 a3 = *(const bf16x8*)(achunk + 3 * 1024 + l * 16);

    const int row_l = w * 16 + (l >> 4) * 4;
#pragma unroll
    for (int nt = 0; nt < 16; ++nt) {
      const char* wb = w_pk + (size_t)nt * 4096 + l * 16;
      bf16x8 b0 = *(const bf16x8*)(wb + 0 * 1024);
      bf16x8 b1 = *(const bf16x8*)(wb + 1 * 1024);
      bf16x8 b2 = *(const bf16x8*)(wb + 2 * 1024);
      bf16x8 b3 = *(const bf16x8*)(wb + 3 * 1024);
      f32x4 acc = {0.f, 0.f, 0.f, 0.f};
      acc = __builtin_amdgcn_mfma_f32_16x16x32_bf16(a0, b0, acc, 0, 0, 0);
      acc = __builtin_amdgcn_mfma_f32_16x16x32_bf16(a1, b1, acc, 0, 0, 0);
      acc = __builtin_amdgcn_mfma_f32_16x16x32_bf16(a2, b2, acc, 0, 0, 0);
      acc = __builtin_amdgcn_mfma_f32_16x16x32_bf16(a3, b3, acc, 0, 0, 0);
      const int col = nt * 16 + (l & 15);
#pragma unroll
      for (int r = 0; r < 4; ++r)
        xm[3 + row_l + r][col] = acc[r];
    }
  }

  if (tile > 0) {
    const char* hchunk = h_pk + (size_t)(b * 64 + tile * 4 - 1) * 4096;
    bf16x8 ha0 = *(const bf16x8*)(hchunk + 0 * 1024 + l * 16);
    bf16x8 ha1 = *(const bf16x8*)(hchunk + 1 * 1024 + l * 16);
    bf16x8 ha2 = *(const bf16x8*)(hchunk + 2 * 1024 + l * 16);
    bf16x8 ha3 = *(const bf16x8*)(hchunk + 3 * 1024 + l * 16);
#pragma unroll
    for (int q = 0; q < 4; ++q) {
      const int nt = w * 4 + q;
      const char* wb = w_pk + (size_t)nt * 4096 + l * 16;
      bf16x8 b0 = *(const bf16x8*)(wb + 0 * 1024);
      bf16x8 b1 = *(const bf16x8*)(wb + 1 * 1024);
      bf16x8 b2 = *(const bf16x8*)(wb + 2 * 1024);
      bf16x8 b3 = *(const bf16x8*)(wb + 3 * 1024);
      f32x4 acc = {0.f, 0.f, 0.f, 0.f};
      acc = __builtin_amdgcn_mfma_f32_16x16x32_bf16(ha0, b0, acc, 0, 0, 0);
      acc = __builtin_amdgcn_mfma_f32_16x16x32_bf16(ha1, b1, acc, 0, 0, 0);
      acc = __builtin_amdgcn_mfma_f32_16x16x32_bf16(ha2, b2, acc, 0, 0, 0);
      acc = __builtin_amdgcn_mfma_f32_16x16x32_bf16(ha3, b3, acc, 0, 0, 0);
      if (l >= 48) {
        const int col = nt * 16 + (l & 15);
        xm[0][col] = acc[1];
        xm[1][col] = acc[2];
        xm[2][col] = acc[3];
      }
    }
  } else {
#pragma unroll
    for (int r = 0; r < 3; ++r) xm[r][tid] = 0.f;
  }
  __syncthreads();

  {
    const int n = tid;
    const float4 cw = *(const float4*)&conv_w[n * 4];
    const float  cb = conv_b[n];
    float x0 = xm[0][n], x1 = xm[1][n], x2 = xm[2][n];
    for (int i = 0; i < 64; ++i) {
      const int t = t0 + i;
      float x3 = xm[3 + i][n];
      if (t < T_LEN) {
        float s = cb + x0 * cw.x + x1 * cw.y + x2 * cw.z + x3 * cw.w;
        u_out[(((size_t)b * T_LEN + t) << 8) + n] = silu_f(s);
      }
      x0 = x1; x1 = x2; x2 = x3;
    }
  }
}

// K3 v14: phase1 dbc GEMM; phase2 thread-per-d emits delta/du BF16
// [b][d][1000] straight from registers (no LDS bounce -- 2 ushort8 stores per
// octet per thread); bm BF16 transposed [b][n][1000]; u_last stashed.
__global__ __launch_bounds__(256) void k3_delta(
    const float* __restrict__ u, const float* __restrict__ x_proj_w,
    const float* __restrict__ dt_proj_w, const float* __restrict__ dt_proj_b,
    unsigned short* __restrict__ delta_bf, unsigned short* __restrict__ du_bf,
    unsigned short* __restrict__ bm_bf, float* __restrict__ u_last)
{
  __shared__ float4 xp4[24][65];
  __shared__ float dt_s[64][9];
  __shared__ float bm_s[64][17];

  const int row0 = blockIdx.x * 64;
  const int tid = threadIdx.x;

  for (int f = tid; f < 24 * 64; f += 256) {
    int c = f >> 6, k4 = f & 63;
    xp4[c][k4] = *(const float4*)&x_proj_w[(size_t)c * 256 + k4 * 4];
  }
  const float4 w0 = *(const float4*)&dt_proj_w[(size_t)tid * 8];
  const float4 w1 = *(const float4*)&dt_proj_w[(size_t)tid * 8 + 4];
  const float bias = dt_proj_b[tid];
  __syncthreads();

  // phase 1
  {
    const int r2 = tid >> 3, cg = tid & 7;
    const int ra = 2 * r2;
    const float4* ua4 = (const float4*)(u + (size_t)(row0 + ra) * 256);
    const float4* ub4 = (const float4*)(u + (size_t)(row0 + ra + 1) * 256);
    float a0 = 0.f, a1 = 0.f, a2 = 0.f, b0 = 0.f, b1 = 0.f, b2 = 0.f;
    for (int k4 = 0; k4 < 64; ++k4) {
      float4 a = ua4[k4], bb = ub4[k4];
      float4 q0 = xp4[cg * 3 + 0][k4];
      float4 q1 = xp4[cg * 3 + 1][k4];
      float4 q2 = xp4[cg * 3 + 2][k4];
      a0 += a.x * q0.x + a.y * q0.y + a.z * q0.z + a.w * q0.w;
      a1 += a.x * q1.x + a.y * q1.y + a.z * q1.z + a.w * q1.w;
      a2 += a.x * q2.x + a.y * q2.y + a.z * q2.z + a.w * q2.w;
      b0 += bb.x * q0.x + bb.y * q0.y + bb.z * q0.z + bb.w * q0.w;
      b1 += bb.x * q1.x + bb.y * q1.y + bb.z * q1.z + bb.w * q1.w;
      b2 += bb.x * q2.x + bb.y * q2.y + bb.z * q2.z + bb.w * q2.w;
    }
    float va[2][3] = {{a0, a1, a2}, {b0, b1, b2}};
#pragma unroll
    for (int rr = 0; rr < 2; ++rr)
#pragma unroll
      for (int c = 0; c < 3; ++c) {
        int col = cg * 3 + c;
        int row = ra + rr;
        if (col < 8) dt_s[row][col] = va[rr][c];
        else bm_s[row][col - 8] = va[rr][c];
      }
  }
  __syncthreads();

  // phase 2: thread = d; 8 octets of 8 t -> bf16 stores from registers
  // (octets never straddle b: 1000 % 8 == 0 and row0 % 8 == 0)
  for (int oct = 0; oct < 8; ++oct) {
    unsigned short pd[8], pu[8];
#pragma unroll
    for (int j = 0; j < 8; ++j) {
      int r = oct * 8 + j;
      float pre = bias
        + dt_s[r][0] * w0.x + dt_s[r][1] * w0.y + dt_s[r][2] * w0.z + dt_s[r][3] * w0.w
        + dt_s[r][4] * w1.x + dt_s[r][5] * w1.y + dt_s[r][6] * w1.z + dt_s[r][7] * w1.w;
      float dlt = softplus_f(pre);
      size_t o = (size_t)(row0 + r) * 256 + tid;
      float uv = u[o];
      pd[j] = f2bf(dlt);
      pu[j] = f2bf(dlt * uv);
      int rowg = row0 + r;
      if ((rowg - (rowg / 1000) * 1000) == 999)
        u_last[(rowg / 1000) * 256 + tid] = uv;
    }
    int rowg = row0 + oct * 8;
    int bb = rowg / 1000;
    int t  = rowg - bb * 1000;
    size_t base = ((size_t)(bb * 256 + tid)) * 1000 + t;
    *(u16x8*)&delta_bf[base] = *(u16x8*)pd;
    *(u16x8*)&du_bf[base]    = *(u16x8*)pu;
  }
  // bm_bf[b][n][1000]: thread = (n, tq); quads never straddle b (1000%4==0)
  {
    const int n = tid >> 4;
    const int tq = tid & 15;
    u16x4 pb;
    pb[0] = f2bf(bm_s[tq * 4 + 0][n]);
    pb[1] = f2bf(bm_s[tq * 4 + 1][n]);
    pb[2] = f2bf(bm_s[tq * 4 + 2][n]);
    pb[3] = f2bf(bm_s[tq * 4 + 3][n]);
    int rowg = row0 + tq * 4;
    int bb = rowg / 1000;
    int t = rowg - bb * 1000;
    *(u16x4*)&bm_bf[((size_t)(bb * 16 + n)) * 1000 + t] = pb;
  }
}

// K4 v19: bf16 LDS staging -- one ds_read_b128 covers 8 steps per operand
// (3 reads / 8 steps = 2.6x fewer LDS-pipe cycles than R18's f32 version,
// which was LDS-issue-bound at 47 cyc/4-steps). 200-step chunks (NCH=5).
__global__ __launch_bounds__(256) void k4_scan(
    const unsigned short* __restrict__ delta_bf,
    const unsigned short* __restrict__ du_bf,
    const unsigned short* __restrict__ bm_bf,
    const float* __restrict__ A_log, float* __restrict__ Qb,
    float* __restrict__ Pb)
{
  __shared__ unsigned short da16[16][200];   // 6.4 KB, rows 400B (16B-aligned)
  __shared__ unsigned short ua16[16][200];   // 6.4 KB
  __shared__ unsigned short bs16[16][200];   // 6.4 KB  [n][t]

  const int d0 = blockIdx.x * 16;
  const int b  = blockIdx.y;
  const int c  = blockIdx.z;
  const int tid = threadIdx.x;
  const int dl = tid >> 4;
  const int n  = tid & 15;
  const int d  = d0 + dl;

  // stage: 400 u16x8 per array, coalesced along rows
  for (int f = tid; f < 400; f += 256) {
    int row = f / 25, col = f - row * 25;
    size_t gd = ((size_t)(b * 256 + d0 + row)) * 1000 + c * 200 + col * 8;
    *(u16x8*)&da16[row][col * 8] = *(const u16x8*)&delta_bf[gd];
    *(u16x8*)&ua16[row][col * 8] = *(const u16x8*)&du_bf[gd];
    size_t gb = ((size_t)(b * 16 + row)) * 1000 + c * 200 + col * 8;
    *(u16x8*)&bs16[row][col * 8] = *(const u16x8*)&bm_bf[gb];
  }
  const float A2 = -expf(A_log[(size_t)d * 16 + n]) * 1.4426950408889634f;
  __syncthreads();

  float s = 0.f, sum = 0.f;
#pragma unroll
  for (int i = 0; i < 25; ++i) {
    u16x8 dv = *(const u16x8*)&da16[dl][8 * i];   // b128: 8 steps of delta
    u16x8 xv = *(const u16x8*)&ua16[dl][8 * i];
    u16x8 bv = *(const u16x8*)&bs16[n][8 * i];
#pragma unroll
    for (int j = 0; j < 8; ++j) {
      float dj = bf2f(dv[j]);
      sum += dj;
      s = fast_exp2(dj * A2) * s + bf2f(xv[j]) * bf2f(bv[j]);
    }
  }

  const size_t o = (size_t)c * 262144 + (size_t)b * 4096 + (size_t)d0 * 16 + tid;
  Qb[o] = s;
  Pb[o] = fast_exp2(A2 * sum);
}

// K4b: fold the NCH affine transitions -> final state.
__global__ __launch_bounds__(256) void k4b_combine(
    const float* __restrict__ Qb, const float* __restrict__ Pb,
    float* __restrict__ state_out)
{
  const size_t g = (size_t)blockIdx.x * 256 + threadIdx.x;   // 1024 blocks
  float s = Qb[g];
#pragma unroll
  for (int c = 1; c < NCH; ++c)
    s = Qb[(size_t)c * 262144 + g] + Pb[(size_t)c * 262144 + g] * s;
  state_out[g] = s;
}

// K5: per-batch head.
__global__ __launch_bounds__(256) void k5_head(
    const float* __restrict__ x, const float* __restrict__ ip_w,
    const float* __restrict__ ip_b, const float* __restrict__ in_proj_w,
    const float* __restrict__ x_proj_w, const float* __restrict__ u_last,
    const float* __restrict__ state, const float* __restrict__ D_skip,
    const float* __restrict__ out_proj_w, const float* __restrict__ fc1_w,
    const float* __restrict__ fc1_b, const float* __restrict__ fc2_w,
    const float* __restrict__ fc2_b, float* __restrict__ out)
{
  const int b = blockIdx.x, tid = threadIdx.x;
  __shared__ float hl[128], ul[256], zs[256], cm[16], yv[256], ov[128], hid[64];
  if (tid < 128) {
    float acc = ip_b[tid];
    const float* xr = x + ((size_t)b * T_LEN + (T_LEN - 1)) * C_IN_;
#pragma unroll
    for (int c = 0; c < C_IN_; ++c) acc += xr[c] * ip_w[tid * C_IN_ + c];
    hl[tid] = acc;
  }
  ul[tid] = u_last[b * 256 + tid];
  __syncthreads();
  {
    float acc = 0.f;
    const float4* wv = (const float4*)(in_proj_w + (size_t)(256 + tid) * 128);
    const float4* h4 = (const float4*)hl;
    for (int k = 0; k < 32; ++k) {
      float4 a = wv[k], c = h4[k];
      acc += c.x * a.x + c.y * a.y + c.z * a.z + c.w * a.w;
    }
    zs[tid] = silu_f(acc);
  }
  if (tid < 16) {
    float acc = 0.f;
    const float4* wv = (const float4*)(x_proj_w + (size_t)(24 + tid) * 256);
    const float4* u4 = (const float4*)ul;
    for (int k = 0; k < 64; ++k) {
      float4 a = wv[k], c = u4[k];
      acc += c.x * a.x + c.y * a.y + c.z * a.z + c.w * a.w;
    }
    cm[tid] = acc;
  }
  __syncthreads();
  {
    const float* st = state + ((size_t)b * 256 + tid) * 16;
    float acc = 0.f;
#pragma unroll
    for (int n = 0; n < 16; ++n) acc += st[n] * cm[n];
    yv[tid] = (acc + ul[tid] * D_skip[tid]) * zs[tid];
  }
  __syncthreads();
  if (tid < 128) {
    float acc = 0.f;
    const float4* wv = (const float4*)(out_proj_w + (size_t)tid * 256);
    const float4* y4 = (const float4*)yv;
    for (int k = 0; k < 64; ++k) {
      float4 a = wv[k], c = y4[k];
      acc += c.x * a.x + c.y * a.y + c.z * a.z + c.w * a.w;
    }
    ov[tid] = acc;
  }
  __syncthreads();
  if (tid < 64) {
    float acc = fc1_b[tid];
    const float4* wv = (const float4*)(fc1_w + (size_t)tid * 128);
    const float4* o4 = (const float4*)ov;
    for (int k = 0; k < 32; ++k) {
      float4 a = wv[k], c = o4[k];
      acc += c.x * a.x + c.y * a.y + c.z * a.z + c.w * a.w;
    }
    hid[tid] = fmaxf(acc, 0.f);
  }
  __syncthreads();
  if (tid < N_CLS) {
    float acc = fc2_b[tid];
    const float* wv = fc2_w + (size_t)tid * 64;
    for (int k = 0; k < 64; ++k) acc += hid[k] * wv[k];
    out[b * N_CLS + tid] = acc;
  }
}

extern "C" void kernel_launch(void* const* d_in, const int* in_sizes, int n_in,
                              void* d_out, int out_size, void* d_ws, size_t ws_size,
                              hipStream_t stream) {
  (void)in_sizes; (void)n_in; (void)out_size; (void)ws_size;
  const float* x         = (const float*)d_in[0];
  const float* ip_w      = (const float*)d_in[1];
  const float* ip_b      = (const float*)d_in[2];
  const float* in_proj_w = (const float*)d_in[3];
  const float* conv_w    = (const float*)d_in[4];
  const float* conv_b    = (const float*)d_in[5];
  const float* x_proj_w  = (const float*)d_in[6];
  const float* dt_proj_w = (const float*)d_in[7];
  const float* dt_proj_b = (const float*)d_in[8];
  const float* A_log     = (const float*)d_in[9];
  const float* D_skip    = (const float*)d_in[10];
  const float* out_proj_w= (const float*)d_in[11];
  const float* fc1_w     = (const float*)d_in[12];
  const float* fc1_b     = (const float*)d_in[13];
  const float* fc2_w     = (const float*)d_in[14];
  const float* fc2_b     = (const float*)d_in[15];
  float* out = (float*)d_out;

  float* u                 = (float*)d_ws;                        // 65.5 MB
  unsigned short* delta_bf = (unsigned short*)(u + 16384000);     // 32.8 MB [b][d][1000]
  unsigned short* du_bf    = delta_bf + (size_t)16384000;         // 32.8 MB
  unsigned short* bm_bf    = du_bf + (size_t)16384000;            //  2.0 MB [b][n][1000]
  float* state             = (float*)(bm_bf + (size_t)1024000);   //  1.0 MB
  float* u_last            = state + (size_t)262144;              // 64 KB  (~134 MB total)
  // aliases into regions dead at their use time (proven pattern):
  char* h_pk = (char*)delta_bf;                 // k0..k1 (delta_bf written by k3 later)
  char* w_pk = h_pk + (size_t)64 * 64 * 4096;
  float* Qb  = u;                               // k4..k4b (u dead after k3)
  float* Pb  = u + (size_t)2000000;             // 1.31M fl each

  k0_prep<<<dim3(17, 64), 256, 0, stream>>>(x, ip_w, ip_b, in_proj_w, h_pk, w_pk);
  k1_u<<<dim3(16, 64), 256, 0, stream>>>(h_pk, w_pk, conv_w, conv_b, u);
  k3_delta<<<1000, 256, 0, stream>>>(u, x_proj_w, dt_proj_w, dt_proj_b,
                                     delta_bf, du_bf, bm_bf, u_last);
  k4_scan<<<dim3(16, 64, NCH), 256, 0, stream>>>(delta_bf, du_bf, bm_bf, A_log, Qb, Pb);
  k4b_combine<<<1024, 256, 0, stream>>>(Qb, Pb, state);
  k5_head<<<64, 256, 0, stream>>>(x, ip_w, ip_b, in_proj_w, x_proj_w, u_last, state,
                                  D_skip, out_proj_w, fc1_w, fc1_b, fc2_w, fc2_b, out);
}

// Round 22
// 194.669 us; speedup vs baseline: 1.4086x; 1.0755x over previous
//
#include <hip/hip_runtime.h>
#include <cstddef>

#define T_LEN 1000
#define B_SZ 64
#define C_IN_ 12
#define D_MODEL_ 128
#define D_INNER_ 256
#define D_STATE_ 16
#define DT_RANK_ 8
#define N_CLS 5
#define NCH 5       // scan time-chunks (200 steps each)

typedef __attribute__((ext_vector_type(8))) short bf16x8;
typedef __attribute__((ext_vector_type(8))) unsigned short u16x8;
typedef __attribute__((ext_vector_type(4))) unsigned short u16x4;
typedef __attribute__((ext_vector_type(4))) float f32x4;

__device__ __forceinline__ float fast_exp2(float x) {
#if __has_builtin(__builtin_amdgcn_exp2f)
  return __builtin_amdgcn_exp2f(x);
#else
  float r; asm volatile("v_exp_f32 %0, %1" : "=v"(r) : "v"(x)); return r;
#endif
}
__device__ __forceinline__ float fast_log2(float x) {
#if __has_builtin(__builtin_amdgcn_logf)
  return __builtin_amdgcn_logf(x);
#else
  float r; asm volatile("v_log_f32 %0, %1" : "=v"(r) : "v"(x)); return r;
#endif
}
__device__ __forceinline__ float fast_rcp(float x) {
#if __has_builtin(__builtin_amdgcn_rcpf)
  return __builtin_amdgcn_rcpf(x);
#else
  float r; asm volatile("v_rcp_f32 %0, %1" : "=v"(r) : "v"(x)); return r;
#endif
}
__device__ __forceinline__ float silu_f(float x) {
  float den = 1.f + fast_exp2(-x * 1.4426950408889634f);
  return x * fast_rcp(den);
}
__device__ __forceinline__ float softplus_f(float x) {
  const float L = 1.4426950408889634f, iL = 0.6931471805599453f;
  float e = fast_exp2(-fabsf(x) * L);
  float l = fast_log2(1.f + e) * iL;
  return fmaxf(x, 0.f) + l;
}
__device__ __forceinline__ unsigned short f2bf(float f) {
  unsigned u = __builtin_bit_cast(unsigned, f);
  u = u + 0x7FFFu + ((u >> 16) & 1u);   // RNE
  return (unsigned short)(u >> 16);
}
__device__ __forceinline__ float bf2f(unsigned short h) {
  unsigned u = ((unsigned)h) << 16;
  return __builtin_bit_cast(float, u);
}

// K0: h = x@ip_w.T + ip_b (bf16, MFMA-frag-packed, zero-filled t>=1000) + W pack.
__global__ __launch_bounds__(256) void k0_prep(
    const float* __restrict__ x, const float* __restrict__ ip_w,
    const float* __restrict__ ip_b, const float* __restrict__ in_proj_w,
    char* __restrict__ h_pk, char* __restrict__ w_pk)
{
  __shared__ unsigned short pk_s[8192];
  __shared__ unsigned short pkw_s[32768];
  const int tid = threadIdx.x;

  if (blockIdx.x == 16) {                    // W-pack block
    if (blockIdx.y != 0) return;
    const int n = tid;
    for (int k = 0; k < D_MODEL_; ++k) {
      unsigned short v = f2bf(in_proj_w[(size_t)n * D_MODEL_ + k]);
      int off = ((n >> 4) * 4 + (k >> 5)) * 512 + ((k & 31) >> 3) * 128
              + (n & 15) * 8 + (k & 7);
      pkw_s[off] = v;
    }
    __syncthreads();
    const float4* s4 = (const float4*)pkw_s;
    float4* dst = (float4*)w_pk;
#pragma unroll
    for (int q = 0; q < 16; ++q) dst[tid * 16 + q] = s4[tid * 16 + q];
    return;
  }

  const int tile4 = blockIdx.x;
  const int b = blockIdx.y;
  const int rl = tid & 63;
  const int kc = (tid >> 6) * 32;
  const int t = tile4 * 64 + rl;

  float xr[C_IN_] = {0.f, 0.f, 0.f, 0.f, 0.f, 0.f, 0.f, 0.f, 0.f, 0.f, 0.f, 0.f};
  const bool valid = (t < T_LEN);
  if (valid) {
    const float4* xp = (const float4*)(x + ((size_t)b * T_LEN + t) * C_IN_);
    float4 v0 = xp[0], v1 = xp[1], v2 = xp[2];
    xr[0] = v0.x; xr[1] = v0.y; xr[2] = v0.z;  xr[3] = v0.w;
    xr[4] = v1.x; xr[5] = v1.y; xr[6] = v1.z;  xr[7] = v1.w;
    xr[8] = v2.x; xr[9] = v2.y; xr[10] = v2.z; xr[11] = v2.w;
  }
  for (int kk = 0; kk < 32; ++kk) {
    const int k = kc + kk;
    unsigned short v = 0;
    if (valid) {
      float acc = ip_b[k];
      const float* wr = ip_w + k * C_IN_;
#pragma unroll
      for (int c = 0; c < C_IN_; ++c) acc += xr[c] * wr[c];
      v = f2bf(acc);
    }
    int off = (rl >> 4) * 2048 + (k >> 5) * 512 + ((k & 31) >> 3) * 128
            + (rl & 15) * 8 + (k & 7);
    pk_s[off] = v;
  }
  __syncthreads();
  const float4* s4 = (const float4*)pk_s;
  float4* dst = (float4*)(h_pk + (size_t)(b * 64 + tile4 * 4) * 4096);
#pragma unroll
  for (int q = 0; q < 4; ++q) dst[tid * 4 + q] = s4[tid * 4 + q];
}

// K1 v10 (R16-proven): MFMA bf16 GEMM; halo rows also via MFMA.
__global__ __launch_bounds__(256) void k1_u(
    const char* __restrict__ h_pk, const char* __restrict__ w_pk,
    const float* __restrict__ conv_w, const float* __restrict__ conv_b,
    float* __restrict__ u_out)
{
  __shared__ float xm[67][260];

  const int tile = blockIdx.x;
  const int b    = blockIdx.y;
  const int t0   = tile * 64;
  const int tid  = threadIdx.x;
  const int w    = tid >> 6;
  const int l    = tid & 63;

  {
    const char* achunk = h_pk + (size_t)(b * 64 + tile * 4 + w) * 4096;
    bf16x8 a0 = *(const bf16x8*)(achunk + 0 * 1024 + l * 16);
    bf16x8 a1 = *(const bf16x8*)(achunk + 1 * 1024 + l * 16);
    bf16x8 a2 = *(const bf16x8*)(achunk + 2 * 1024 + l * 16);
    bf16x8 a3 = *(const bf16x8*)(achunk + 3 * 1024 + l * 16);

    const int row_l = w * 16 + (l >> 4) * 4;
#pragma unroll
    for (int nt = 0; nt < 16; ++nt) {
      const char* wb = w_pk + (size_t)nt * 4096 + l * 16;
      bf16x8 b0 = *(const bf16x8*)(wb + 0 * 1024);
      bf16x8 b1 = *(const bf16x8*)(wb + 1 * 1024);
      bf16x8 b2 = *(const bf16x8*)(wb + 2 * 1024);
      bf16x8 b3 = *(const bf16x8*)(wb + 3 * 1024);
      f32x4 acc = {0.f, 0.f, 0.f, 0.f};
      acc = __builtin_amdgcn_mfma_f32_16x16x32_bf16(a0, b0, acc, 0, 0, 0);
      acc = __builtin_amdgcn_mfma_f32_16x16x32_bf16(a1, b1, acc, 0, 0, 0);
      acc = __builtin_amdgcn_mfma_f32_16x16x32_bf16(a2, b2, acc, 0, 0, 0);
      acc = __builtin_amdgcn_mfma_f32_16x16x32_bf16(a3, b3, acc, 0, 0, 0);
      const int col = nt * 16 + (l & 15);
#pragma unroll
      for (int r = 0; r < 4; ++r)
        xm[3 + row_l + r][col] = acc[r];
    }
  }

  if (tile > 0) {
    const char* hchunk = h_pk + (size_t)(b * 64 + tile * 4 - 1) * 4096;
    bf16x8 ha0 = *(const bf16x8*)(hchunk + 0 * 1024 + l * 16);
    bf16x8 ha1 = *(const bf16x8*)(hchunk + 1 * 1024 + l * 16);
    bf16x8 ha2 = *(const bf16x8*)(hchunk + 2 * 1024 + l * 16);
    bf16x8 ha3 = *(const bf16x8*)(hchunk + 3 * 1024 + l * 16);
#pragma unroll
    for (int q = 0; q < 4; ++q) {
      const int nt = w * 4 + q;
      const char* wb = w_pk + (size_t)nt * 4096 + l * 16;
      bf16x8 b0 = *(const bf16x8*)(wb + 0 * 1024);
      bf16x8 b1 = *(const bf16x8*)(wb + 1 * 1024);
      bf16x8 b2 = *(const bf16x8*)(wb + 2 * 1024);
      bf16x8 b3 = *(const bf16x8*)(wb + 3 * 1024);
      f32x4 acc = {0.f, 0.f, 0.f, 0.f};
      acc = __builtin_amdgcn_mfma_f32_16x16x32_bf16(ha0, b0, acc, 0, 0, 0);
      acc = __builtin_amdgcn_mfma_f32_16x16x32_bf16(ha1, b1, acc, 0, 0, 0);
      acc = __builtin_amdgcn_mfma_f32_16x16x32_bf16(ha2, b2, acc, 0, 0, 0);
      acc = __builtin_amdgcn_mfma_f32_16x16x32_bf16(ha3, b3, acc, 0, 0, 0);
      if (l >= 48) {
        const int col = nt * 16 + (l & 15);
        xm[0][col] = acc[1];
        xm[1][col] = acc[2];
        xm[2][col] = acc[3];
      }
    }
  } else {
#pragma unroll
    for (int r = 0; r < 3; ++r) xm[r][tid] = 0.f;
  }
  __syncthreads();

  {
    const int n = tid;
    const float4 cw = *(const float4*)&conv_w[n * 4];
    const float  cb = conv_b[n];
    float x0 = xm[0][n], x1 = xm[1][n], x2 = xm[2][n];
    for (int i = 0; i < 64; ++i) {
      const int t = t0 + i;
      float x3 = xm[3 + i][n];
      if (t < T_LEN) {
        float s = cb + x0 * cw.x + x1 * cw.y + x2 * cw.z + x3 * cw.w;
        u_out[(((size_t)b * T_LEN + t) << 8) + n] = silu_f(s);
      }
      x0 = x1; x1 = x2; x2 = x3;
    }
  }
}

// K3 v16: phase1 dbc GEMM; phase2 emits delta/du BF16 [b][d][1000] via LDS
// transpose (two 32-t super-chunks, pad-35 tiles -> 2-way-free banks; stores
// are 4 lanes x u16x8 = FULL 64B line per d-row per instruction -- fixes
// R20's 2.4x write amplification). bm bf16 transposed; u_last stashed.
__global__ __launch_bounds__(256) void k3_delta(
    const float* __restrict__ u, const float* __restrict__ x_proj_w,
    const float* __restrict__ dt_proj_w, const float* __restrict__ dt_proj_b,
    unsigned short* __restrict__ delta_bf, unsigned short* __restrict__ du_bf,
    unsigned short* __restrict__ bm_bf, float* __restrict__ u_last)
{
  __shared__ __align__(16) float smem[2 * 256 * 35];   // 71.7 KB
  float4 (*xp4)[65] = reinterpret_cast<float4(*)[65]>(smem);  // phase-1 view (25 KB)
  float* txd = smem;                                          // phase-2: delta tile
  float* txu = smem + 256 * 35;                               // phase-2: du tile
  __shared__ float dt_s[64][9];
  __shared__ float bm_s[64][17];

  const int row0 = blockIdx.x * 64;
  const int tid = threadIdx.x;

  for (int f = tid; f < 24 * 64; f += 256) {
    int c = f >> 6, k4 = f & 63;
    xp4[c][k4] = *(const float4*)&x_proj_w[(size_t)c * 256 + k4 * 4];
  }
  const float4 w0 = *(const float4*)&dt_proj_w[(size_t)tid * 8];
  const float4 w1 = *(const float4*)&dt_proj_w[(size_t)tid * 8 + 4];
  const float bias = dt_proj_b[tid];
  __syncthreads();

  // phase 1
  {
    const int r2 = tid >> 3, cg = tid & 7;
    const int ra = 2 * r2;
    const float4* ua4 = (const float4*)(u + (size_t)(row0 + ra) * 256);
    const float4* ub4 = (const float4*)(u + (size_t)(row0 + ra + 1) * 256);
    float a0 = 0.f, a1 = 0.f, a2 = 0.f, b0 = 0.f, b1 = 0.f, b2 = 0.f;
    for (int k4 = 0; k4 < 64; ++k4) {
      float4 a = ua4[k4], bb = ub4[k4];
      float4 q0 = xp4[cg * 3 + 0][k4];
      float4 q1 = xp4[cg * 3 + 1][k4];
      float4 q2 = xp4[cg * 3 + 2][k4];
      a0 += a.x * q0.x + a.y * q0.y + a.z * q0.z + a.w * q0.w;
      a1 += a.x * q1.x + a.y * q1.y + a.z * q1.z + a.w * q1.w;
      a2 += a.x * q2.x + a.y * q2.y + a.z * q2.z + a.w * q2.w;
      b0 += bb.x * q0.x + bb.y * q0.y + bb.z * q0.z + bb.w * q0.w;
      b1 += bb.x * q1.x + bb.y * q1.y + bb.z * q1.z + bb.w * q1.w;
      b2 += bb.x * q2.x + bb.y * q2.y + bb.z * q2.z + bb.w * q2.w;
    }
    float va[2][3] = {{a0, a1, a2}, {b0, b1, b2}};
#pragma unroll
    for (int rr = 0; rr < 2; ++rr)
#pragma unroll
      for (int c = 0; c < 3; ++c) {
        int col = cg * 3 + c;
        int row = ra + rr;
        if (col < 8) dt_s[row][col] = va[rr][c];
        else bm_s[row][col - 8] = va[rr][c];
      }
  }
  __syncthreads();   // phase-1 xp4 reads done; txd/txu may overwrite

  // phase 2: two super-chunks of 32 t
  for (int sc = 0; sc < 2; ++sc) {
    // compute 32 rows into tx tiles (thread = d, row-private writes, 2L%32 free)
#pragma unroll
    for (int j = 0; j < 32; ++j) {
      int r = sc * 32 + j;
      float pre = bias
        + dt_s[r][0] * w0.x + dt_s[r][1] * w0.y + dt_s[r][2] * w0.z + dt_s[r][3] * w0.w
        + dt_s[r][4] * w1.x + dt_s[r][5] * w1.y + dt_s[r][6] * w1.z + dt_s[r][7] * w1.w;
      float dlt = softplus_f(pre);
      size_t o = (size_t)(row0 + r) * 256 + tid;
      float uv = u[o];
      txd[tid * 35 + j] = dlt;
      txu[tid * 35 + j] = dlt * uv;
      int rowg = row0 + r;
      if ((rowg - (rowg / 1000) * 1000) == 999)
        u_last[(rowg / 1000) * 256 + tid] = uv;
    }
    __syncthreads();
    // transpose-store: 4 passes x (64 d-rows, 4 lanes x 16B = full 64B line/row)
#pragma unroll
    for (int p = 0; p < 4; ++p) {
      const int d_ = p * 64 + (tid >> 2);
      const int t8 = (tid & 3) * 8;
      unsigned short pd[8], pu[8];
#pragma unroll
      for (int j = 0; j < 8; ++j) {
        pd[j] = f2bf(txd[d_ * 35 + t8 + j]);
        pu[j] = f2bf(txu[d_ * 35 + t8 + j]);
      }
      int rowg = row0 + sc * 32 + t8;     // octet never straddles b (1000%8==0)
      int bb = rowg / 1000;
      int t = rowg - bb * 1000;
      size_t base = ((size_t)(bb * 256 + d_)) * 1000 + t;
      *(u16x8*)&delta_bf[base] = *(u16x8*)pd;
      *(u16x8*)&du_bf[base]    = *(u16x8*)pu;
    }
    __syncthreads();
  }
  // bm_bf[b][n][1000]: thread = (n, tq); quads never straddle b (1000%4==0)
  {
    const int n = tid >> 4;
    const int tq = tid & 15;
    u16x4 pb;
    pb[0] = f2bf(bm_s[tq * 4 + 0][n]);
    pb[1] = f2bf(bm_s[tq * 4 + 1][n]);
    pb[2] = f2bf(bm_s[tq * 4 + 2][n]);
    pb[3] = f2bf(bm_s[tq * 4 + 3][n]);
    int rowg = row0 + tq * 4;
    int bb = rowg / 1000;
    int t = rowg - bb * 1000;
    *(u16x4*)&bm_bf[((size_t)(bb * 16 + n)) * 1000 + t] = pb;
  }
}

// K4 v19 (R20-measured best): bf16 LDS staging, one ds_read_b128 per 8 steps
// per operand. 200-step chunks (NCH=5).
__global__ __launch_bounds__(256) void k4_scan(
    const unsigned short* __restrict__ delta_bf,
    const unsigned short* __restrict__ du_bf,
    const unsigned short* __restrict__ bm_bf,
    const float* __restrict__ A_log, float* __restrict__ Qb,
    float* __restrict__ Pb)
{
  __shared__ unsigned short da16[16][200];
  __shared__ unsigned short ua16[16][200];
  __shared__ unsigned short bs16[16][200];

  const int d0 = blockIdx.x * 16;
  const int b  = blockIdx.y;
  const int c  = blockIdx.z;
  const int tid = threadIdx.x;
  const int dl = tid >> 4;
  const int n  = tid & 15;
  const int d  = d0 + dl;

  for (int f = tid; f < 400; f += 256) {
    int row = f / 25, col = f - row * 25;
    size_t gd = ((size_t)(b * 256 + d0 + row)) * 1000 + c * 200 + col * 8;
    *(u16x8*)&da16[row][col * 8] = *(const u16x8*)&delta_bf[gd];
    *(u16x8*)&ua16[row][col * 8] = *(const u16x8*)&du_bf[gd];
    size_t gb = ((size_t)(b * 16 + row)) * 1000 + c * 200 + col * 8;
    *(u16x8*)&bs16[row][col * 8] = *(const u16x8*)&bm_bf[gb];
  }
  const float A2 = -expf(A_log[(size_t)d * 16 + n]) * 1.4426950408889634f;
  __syncthreads();

  float s = 0.f, sum = 0.f;
#pragma unroll
  for (int i = 0; i < 25; ++i) {
    u16x8 dv = *(const u16x8*)&da16[dl][8 * i];
    u16x8 xv = *(const u16x8*)&ua16[dl][8 * i];
    u16x8 bv = *(const u16x8*)&bs16[n][8 * i];
#pragma unroll
    for (int j = 0; j < 8; ++j) {
      float dj = bf2f(dv[j]);
      sum += dj;
      s = fast_exp2(dj * A2) * s + bf2f(xv[j]) * bf2f(bv[j]);
    }
  }

  const size_t o = (size_t)c * 262144 + (size_t)b * 4096 + (size_t)d0 * 16 + tid;
  Qb[o] = s;
  Pb[o] = fast_exp2(A2 * sum);
}

// K4b: fold the NCH affine transitions -> final state.
__global__ __launch_bounds__(256) void k4b_combine(
    const float* __restrict__ Qb, const float* __restrict__ Pb,
    float* __restrict__ state_out)
{
  const size_t g = (size_t)blockIdx.x * 256 + threadIdx.x;   // 1024 blocks
  float s = Qb[g];
#pragma unroll
  for (int c = 1; c < NCH; ++c)
    s = Qb[(size_t)c * 262144 + g] + Pb[(size_t)c * 262144 + g] * s;
  state_out[g] = s;
}

// K5: per-batch head.
__global__ __launch_bounds__(256) void k5_head(
    const float* __restrict__ x, const float* __restrict__ ip_w,
    const float* __restrict__ ip_b, const float* __restrict__ in_proj_w,
    const float* __restrict__ x_proj_w, const float* __restrict__ u_last,
    const float* __restrict__ state, const float* __restrict__ D_skip,
    const float* __restrict__ out_proj_w, const float* __restrict__ fc1_w,
    const float* __restrict__ fc1_b, const float* __restrict__ fc2_w,
    const float* __restrict__ fc2_b, float* __restrict__ out)
{
  const int b = blockIdx.x, tid = threadIdx.x;
  __shared__ float hl[128], ul[256], zs[256], cm[16], yv[256], ov[128], hid[64];
  if (tid < 128) {
    float acc = ip_b[tid];
    const float* xr = x + ((size_t)b * T_LEN + (T_LEN - 1)) * C_IN_;
#pragma unroll
    for (int c = 0; c < C_IN_; ++c) acc += xr[c] * ip_w[tid * C_IN_ + c];
    hl[tid] = acc;
  }
  ul[tid] = u_last[b * 256 + tid];
  __syncthreads();
  {
    float acc = 0.f;
    const float4* wv = (const float4*)(in_proj_w + (size_t)(256 + tid) * 128);
    const float4* h4 = (const float4*)hl;
    for (int k = 0; k < 32; ++k) {
      float4 a = wv[k], c = h4[k];
      acc += c.x * a.x + c.y * a.y + c.z * a.z + c.w * a.w;
    }
    zs[tid] = silu_f(acc);
  }
  if (tid < 16) {
    float acc = 0.f;
    const float4* wv = (const float4*)(x_proj_w + (size_t)(24 + tid) * 256);
    const float4* u4 = (const float4*)ul;
    for (int k = 0; k < 64; ++k) {
      float4 a = wv[k], c = u4[k];
      acc += c.x * a.x + c.y * a.y + c.z * a.z + c.w * a.w;
    }
    cm[tid] = acc;
  }
  __syncthreads();
  {
    const float* st = state + ((size_t)b * 256 + tid) * 16;
    float acc = 0.f;
#pragma unroll
    for (int n = 0; n < 16; ++n) acc += st[n] * cm[n];
    yv[tid] = (acc + ul[tid] * D_skip[tid]) * zs[tid];
  }
  __syncthreads();
  if (tid < 128) {
    float acc = 0.f;
    const float4* wv = (const float4*)(out_proj_w + (size_t)tid * 256);
    const float4* y4 = (const float4*)yv;
    for (int k = 0; k < 64; ++k) {
      float4 a = wv[k], c = y4[k];
      acc += c.x * a.x + c.y * a.y + c.z * a.z + c.w * a.w;
    }
    ov[tid] = acc;
  }
  __syncthreads();
  if (tid < 64) {
    float acc = fc1_b[tid];
    const float4* wv = (const float4*)(fc1_w + (size_t)tid * 128);
    const float4* o4 = (const float4*)ov;
    for (int k = 0; k < 32; ++k) {
      float4 a = wv[k], c = o4[k];
      acc += c.x * a.x + c.y * a.y + c.z * a.z + c.w * a.w;
    }
    hid[tid] = fmaxf(acc, 0.f);
  }
  __syncthreads();
  if (tid < N_CLS) {
    float acc = fc2_b[tid];
    const float* wv = fc2_w + (size_t)tid * 64;
    for (int k = 0; k < 64; ++k) acc += hid[k] * wv[k];
    out[b * N_CLS + tid] = acc;
  }
}

extern "C" void kernel_launch(void* const* d_in, const int* in_sizes, int n_in,
                              void* d_out, int out_size, void* d_ws, size_t ws_size,
                              hipStream_t stream) {
  (void)in_sizes; (void)n_in; (void)out_size; (void)ws_size;
  const float* x         = (const float*)d_in[0];
  const float* ip_w      = (const float*)d_in[1];
  const float* ip_b      = (const float*)d_in[2];
  const float* in_proj_w = (const float*)d_in[3];
  const float* conv_w    = (const float*)d_in[4];
  const float* conv_b    = (const float*)d_in[5];
  const float* x_proj_w  = (const float*)d_in[6];
  const float* dt_proj_w = (const float*)d_in[7];
  const float* dt_proj_b = (const float*)d_in[8];
  const float* A_log     = (const float*)d_in[9];
  const float* D_skip    = (const float*)d_in[10];
  const float* out_proj_w= (const float*)d_in[11];
  const float* fc1_w     = (const float*)d_in[12];
  const float* fc1_b     = (const float*)d_in[13];
  const float* fc2_w     = (const float*)d_in[14];
  const float* fc2_b     = (const float*)d_in[15];
  float* out = (float*)d_out;

  float* u                 = (float*)d_ws;                        // 65.5 MB
  unsigned short* delta_bf = (unsigned short*)(u + 16384000);     // 32.8 MB [b][d][1000]
  unsigned short* du_bf    = delta_bf + (size_t)16384000;         // 32.8 MB
  unsigned short* bm_bf    = du_bf + (size_t)16384000;            //  2.0 MB [b][n][1000]
  float* state             = (float*)(bm_bf + (size_t)1024000);   //  1.0 MB
  float* u_last            = state + (size_t)262144;              // 64 KB
  // aliases into regions dead at their use time (proven pattern):
  char* h_pk = (char*)delta_bf;                 // k0..k1 (delta_bf written by k3 later)
  char* w_pk = h_pk + (size_t)64 * 64 * 4096;
  float* Qb  = u;                               // k4..k4b (u dead after k3)
  float* Pb  = u + (size_t)2000000;             // 1.31M fl each

  k0_prep<<<dim3(17, 64), 256, 0, stream>>>(x, ip_w, ip_b, in_proj_w, h_pk, w_pk);
  k1_u<<<dim3(16, 64), 256, 0, stream>>>(h_pk, w_pk, conv_w, conv_b, u);
  k3_delta<<<1000, 256, 0, stream>>>(u, x_proj_w, dt_proj_w, dt_proj_b,
                                     delta_bf, du_bf, bm_bf, u_last);
  k4_scan<<<dim3(16, 64, NCH), 256, 0, stream>>>(delta_bf, du_bf, bm_bf, A_log, Qb, Pb);
  k4b_combine<<<1024, 256, 0, stream>>>(Qb, Pb, state);
  k5_head<<<64, 256, 0, stream>>>(x, ip_w, ip_b, in_proj_w, x_proj_w, u_last, state,
                                  D_skip, out_proj_w, fc1_w, fc1_b, fc2_w, fc2_b, out);
}